// Round 1
// 114.984 us; speedup vs baseline: 1.5372x; 1.5372x over previous
//
#include <hip/hip_runtime.h>

// 4-level db4 wavedec (symmetric mode) + 6 stats per band.
// One block of 512 threads per signal. Levels: 16384 -> 8195 -> 4101 -> 2054 -> 1030.
//
// V2 structure (vs in-place V1 @177us):
//  - pair-per-thread: thread k computes outputs (2k, 2k+1) from one 16-float
//    window [4k-8, 4k+8) loaded as 4x float4 (16B aligned) ->
//    global_load_dwordx4 at L1 (perfect coalescing), ds_read_b128 at L2-4
//    (16B lane stride = conflict-free: 8 lanes cover all 32 banks evenly).
//  - zero-crossing via an extra local d(2k+2) dot-product (window already
//    loaded) -> both zc comparisons are thread-local, no shuffles/LDS.
//  - ping-pong LDS buffers A(8196)/B(4104): no in-place hazard -> exactly
//    one __syncthreads between levels (5 total vs ~44 in V1).
//  - deferred reduction: per-band wave partials -> red[5][8][5], single final
//    barrier, lanes 0..4 finalize one band each.
//  - LDS ~50KB -> 3 blocks/CU * 8 waves = 24 waves/CU. launch_bounds(512,6)
//    targets VGPR<=85 so LDS (not VGPR) is the occupancy limit.
// Band order in output: [cA4, cD4, cD3, cD2, cD1] x [mean_abs, std, rms, max, energy, zc].

#define T0 16384
#define BLK 512
#define NW (BLK / 64)

// Reversed db4 decomposition filters (lax correlation == pywt convolution).
__device__ __constant__ float HLO[8] = {
     0.23037781330885523f,  0.7148465705525415f,   0.6308807679295904f,
    -0.02798376941698385f, -0.18703481171888114f,  0.030841381835986965f,
     0.032883011666982945f, -0.010597401784997278f };
__device__ __constant__ float HHI[8] = {
    -0.010597401784997278f, -0.032883011666982945f, 0.030841381835986965f,
     0.18703481171888114f,  -0.02798376941698385f,  -0.6308807679295904f,
     0.7148465705525415f,   -0.23037781330885523f };

__device__ __forceinline__ float signf(float v) {
    return (v > 0.f) ? 1.f : ((v < 0.f) ? -1.f : 0.f);
}

// symmetric extension fold: ext index t (relative to signal start) -> valid index.
// Single fold valid for -L <= t <= 2L-1; our windows stay within [-8, L+12].
__device__ __forceinline__ float getsym(const float* __restrict__ s, int t, int L) {
    if (t < 0) t = -1 - t;
    else if (t >= L) t = 2 * L - 1 - t;
    return s[t];
}

// Wave-level butterfly reduce of the 5 partials; lane0 of each wave writes
// its slot in red[band][wave][5]. NO barrier here (deferred to finalize).
__device__ __forceinline__ void band_reduce(float sabs, float ssum, float ssq,
                                            float smax, float zc,
                                            int band, float* __restrict__ red) {
    #pragma unroll
    for (int off = 32; off > 0; off >>= 1) {
        sabs += __shfl_xor(sabs, off, 64);
        ssum += __shfl_xor(ssum, off, 64);
        ssq  += __shfl_xor(ssq,  off, 64);
        smax  = fmaxf(smax, __shfl_xor(smax, off, 64));
        zc   += __shfl_xor(zc,   off, 64);
    }
    const int lane = threadIdx.x & 63;
    const int wave = threadIdx.x >> 6;
    if (lane == 0) {
        float* r = red + (band * NW + wave) * 5;
        r[0] = sabs; r[1] = ssum; r[2] = ssq; r[3] = smax; r[4] = zc;
    }
}

// One DWT level: src[0..L) -> cA into dst[0..o), cD stats into red[band].
// Thread k handles output pair (2k, 2k+1) + an extra d(2k+2) for the odd zc
// comparison. Must be inlined so the LDS/global address spaces specialize.
__device__ __forceinline__ void dwt_level(const float* __restrict__ src, int L,
                                          float* __restrict__ dst, int o,
                                          int band, float* __restrict__ red) {
    float sabs = 0.f, ssum = 0.f, ssq = 0.f, smax = 0.f, zc = 0.f;
    const int npairs = (o + 1) >> 1;
    for (int k = threadIdx.x; k < npairs; k += BLK) {
        const int w = 4 * k - 8;          // 16B-aligned window start
        float v[16];
        if (w >= 0 && w + 16 <= L) {
            const float4* p4 = reinterpret_cast<const float4*>(src + w);
            const float4 q0 = p4[0], q1 = p4[1], q2 = p4[2], q3 = p4[3];
            v[0]  = q0.x; v[1]  = q0.y; v[2]  = q0.z; v[3]  = q0.w;
            v[4]  = q1.x; v[5]  = q1.y; v[6]  = q1.z; v[7]  = q1.w;
            v[8]  = q2.x; v[9]  = q2.y; v[10] = q2.z; v[11] = q2.w;
            v[12] = q3.x; v[13] = q3.y; v[14] = q3.z; v[15] = q3.w;
        } else {
            #pragma unroll
            for (int j = 0; j < 16; ++j) v[j] = getsym(src, w + j, L);
        }
        // output p=2k uses ext[2p-6 .. 2p+1] = v[2..9]; p+1 -> v[4..11]; p+2 -> v[6..13]
        float a0 = 0.f, d0 = 0.f, a1 = 0.f, d1 = 0.f, d2 = 0.f;
        #pragma unroll
        for (int m = 0; m < 8; ++m) {
            const float lo = HLO[m], hi = HHI[m];
            a0 = fmaf(v[m + 2], lo, a0);
            d0 = fmaf(v[m + 2], hi, d0);
            a1 = fmaf(v[m + 4], lo, a1);
            d1 = fmaf(v[m + 4], hi, d1);
            d2 = fmaf(v[m + 6], hi, d2);
        }
        const int p0 = 2 * k;
        const bool v1ok = (p0 + 1 < o);
        if (v1ok) {
            *reinterpret_cast<float2*>(dst + p0) = make_float2(a0, a1);  // ds_write_b64
        } else {
            dst[p0] = a0;                  // last output of odd-length bands
        }
        const float ad0 = fabsf(d0);
        sabs += ad0; ssum += d0; ssq = fmaf(d0, d0, ssq); smax = fmaxf(smax, ad0);
        if (v1ok) {
            const float ad1 = fabsf(d1);
            sabs += ad1; ssum += d1; ssq = fmaf(d1, d1, ssq); smax = fmaxf(smax, ad1);
            const float s0 = signf(d0), s1 = signf(d1);
            if (s0 != s1) zc += 1.f;                           // pair (2k, 2k+1)
            if (p0 + 2 < o && s1 != signf(d2)) zc += 1.f;      // pair (2k+1, 2k+2)
        }
    }
    band_reduce(sabs, ssum, ssq, smax, zc, band, red);
}

// Features of the final cA4 band (resident in LDS).
__device__ __forceinline__ void feat_band(const float* __restrict__ c, int o,
                                          int band, float* __restrict__ red) {
    float sabs = 0.f, ssum = 0.f, ssq = 0.f, smax = 0.f, zc = 0.f;
    for (int i = threadIdx.x; i < o; i += BLK) {
        const float x0 = c[i];
        const float a0 = fabsf(x0);
        sabs += a0; ssum += x0; ssq = fmaf(x0, x0, ssq); smax = fmaxf(smax, a0);
        if (i + 1 < o) {
            if (signf(x0) != signf(c[i + 1])) zc += 1.f;
        }
    }
    band_reduce(sabs, ssum, ssq, smax, zc, band, red);
}

__global__ void __launch_bounds__(BLK, 6)
wavelet_feat_kernel(const float* __restrict__ x, float* __restrict__ out) {
    __shared__ __align__(16) float A[8196];     // cA1, later cA3
    __shared__ __align__(16) float B[4104];     // cA2, later cA4
    __shared__ float red[5 * NW * 5];           // [band][wave][stat]

    const int sig = blockIdx.x;
    const float* src0 = x + (size_t)sig * T0;
    float* outp = out + (size_t)sig * 30;

    // band index: 0=cA4 1=cD4 2=cD3 3=cD2 4=cD1
    dwt_level(src0, T0,   A, 8195, 4, red);   // L1: global -> A, cD1 stats
    __syncthreads();
    dwt_level(A,    8195, B, 4101, 3, red);   // L2: A -> B, cD2
    __syncthreads();
    dwt_level(B,    4101, A, 2054, 2, red);   // L3: B -> A (clobbers cA1), cD3
    __syncthreads();
    dwt_level(A,    2054, B, 1030, 1, red);   // L4: A -> B (clobbers cA2), cD4
    __syncthreads();
    feat_band(B,    1030, 0, red);            // cA4 stats
    __syncthreads();                          // red[] complete

    if (threadIdx.x < 5) {
        const int band = threadIdx.x;
        float a = 0.f, s = 0.f, q = 0.f, m = 0.f, z = 0.f;
        #pragma unroll
        for (int w = 0; w < NW; ++w) {
            const float* r = red + (band * NW + w) * 5;
            a += r[0]; s += r[1]; q += r[2]; m = fmaxf(m, r[3]); z += r[4];
        }
        const int o = (band <= 1) ? 1030 : (band == 2 ? 2054 : (band == 3 ? 4101 : 8195));
        const float inv  = 1.0f / (float)o;
        const float mean = s * inv;
        const float var  = q * inv - mean * mean;
        float* op = outp + band * 6;
        op[0] = a * inv;                  // mean_abs
        op[1] = sqrtf(fmaxf(var, 0.f));   // std (population)
        op[2] = sqrtf(q * inv);           // rms
        op[3] = m;                        // max_abs
        op[4] = q;                        // energy
        op[5] = z * inv;                  // zero-crossing rate
    }
}

extern "C" void kernel_launch(void* const* d_in, const int* in_sizes, int n_in,
                              void* d_out, int out_size, void* d_ws, size_t ws_size,
                              hipStream_t stream) {
    const float* x = (const float*)d_in[0];
    float* out = (float*)d_out;
    const int nsig = in_sizes[0] / T0;   // 64*64 = 4096
    hipLaunchKernelGGL(wavelet_feat_kernel, dim3(nsig), dim3(BLK), 0, stream, x, out);
}

// Round 2
// 90.064 us; speedup vs baseline: 1.9626x; 1.2767x over previous
//
#include <hip/hip_runtime.h>

// 4-level db4 wavedec (symmetric mode) + 6 stats per band.
// One block of 512 threads per signal. Levels: 16384 -> 8195 -> 4101 -> 2054 -> 1030.
//
// V3 (vs V2 pair-per-thread @115us):
//  - quad-per-thread: thread k computes outputs 4k..4k+3 (+ extra a/d at 4k+4
//    for thread-local zero-crossing) from one 20-float window [8k-8, 8k+12)
//    loaded as 5x float4 / ds_read_b128. MAC/output 20->18, bytes/output
//    32->20, addressing & loop overhead halved vs pair version.
//  - L4 fused stats: cA4 is never materialized; its 6 features are accumulated
//    from registers inside the L4 loop (kills feat_band pass + 1 barrier).
//  - sign-bit zero-crossing: (as_int(a)^as_int(b))<0, ~3 ops vs ~10 for signf.
//  - exact main/tail split: nq_main=(o-1)>>2 full quads need NO validity
//    guards (L1: exactly 4 iters/thread); the single leftover quad per level
//    runs guarded on thread 511 (low threads absorb main-loop remainders).
//  - ping-pong LDS A(8196)/B(4104), 4 barriers total, deferred reduction.
// Band order in output: [cA4, cD4, cD3, cD2, cD1] x [mean_abs, std, rms, max, energy, zc].

#define T0 16384
#define BLK 512
#define NW (BLK / 64)

// Reversed db4 decomposition filters (lax correlation == pywt convolution).
// constexpr so fully-unrolled dots see compile-time constants (-> s_mov + FMA).
constexpr float FLO[8] = {
     0.23037781330885523f,  0.7148465705525415f,   0.6308807679295904f,
    -0.02798376941698385f, -0.18703481171888114f,  0.030841381835986965f,
     0.032883011666982945f, -0.010597401784997278f };
constexpr float FHI[8] = {
    -0.010597401784997278f, -0.032883011666982945f, 0.030841381835986965f,
     0.18703481171888114f,  -0.02798376941698385f,  -0.6308807679295904f,
     0.7148465705525415f,   -0.23037781330885523f };

// symmetric extension fold: ext index t (relative to signal start) -> valid index.
// Single fold valid for -L <= t <= 2L-1; our windows stay within [-6, L+10].
__device__ __forceinline__ float getsym(const float* __restrict__ s, int t, int L) {
    if (t < 0) t = -1 - t;
    else if (t >= L) t = 2 * L - 1 - t;
    return s[t];
}

// 1 if sign bits differ (zero-crossing), as float. Matches sign()-diff
// semantics for nonzero data (exact zeros have probability ~0).
__device__ __forceinline__ float zcstep(float p, float q) {
    return ((__float_as_int(p) ^ __float_as_int(q)) < 0) ? 1.f : 0.f;
}

// Wave-level butterfly reduce of the 5 partials; lane0 of each wave writes
// its slot in red[band][wave][5]. NO barrier here (deferred to finalize).
__device__ __forceinline__ void band_reduce(float sabs, float ssum, float ssq,
                                            float smax, float zc,
                                            int band, float* __restrict__ red) {
    #pragma unroll
    for (int off = 32; off > 0; off >>= 1) {
        sabs += __shfl_xor(sabs, off, 64);
        ssum += __shfl_xor(ssum, off, 64);
        ssq  += __shfl_xor(ssq,  off, 64);
        smax  = fmaxf(smax, __shfl_xor(smax, off, 64));
        zc   += __shfl_xor(zc,   off, 64);
    }
    const int lane = threadIdx.x & 63;
    const int wave = threadIdx.x >> 6;
    if (lane == 0) {
        float* r = red + (band * NW + wave) * 5;
        r[0] = sabs; r[1] = ssum; r[2] = ssq; r[3] = smax; r[4] = zc;
    }
}

// One DWT level, quad-per-thread.
//   out[p] = sum_m src_ext[2p-6+m] * F[m];  v[j] = src_ext[8k-8+j], j in [2,18)
//   output p=4k+i uses v[2i+2 .. 2i+9] (i=0..4; i=4 is the zc-extra).
// LAST: also accumulate cA stats into band 0 and skip the dst write.
template<bool LAST>
__device__ __forceinline__ void dwt_quad_level(const float* __restrict__ src, int L,
                                               float* __restrict__ dst, int o,
                                               int dband, float* __restrict__ red) {
    float sabs = 0.f, ssum = 0.f, ssq = 0.f, smax = 0.f, zc = 0.f;       // cD stats
    float sabsA = 0.f, ssumA = 0.f, ssqA = 0.f, smaxA = 0.f, zcA = 0.f;  // cA stats (LAST)
    const int nq_main = (o - 1) >> 2;   // quads with 4 valid outputs AND valid extra

    for (int k = threadIdx.x; k < nq_main; k += BLK) {
        const int w = 8 * k - 8;
        float v[20];
        if (w >= 0 && w + 20 <= L) {
            #pragma unroll
            for (int q = 0; q < 5; ++q) {
                const float4 t = *reinterpret_cast<const float4*>(src + w + 4 * q);
                v[4*q+0] = t.x; v[4*q+1] = t.y; v[4*q+2] = t.z; v[4*q+3] = t.w;
            }
        } else {
            #pragma unroll
            for (int j = 2; j < 18; ++j) v[j] = getsym(src, w + j, L);
        }
        float a[5], d[5];
        #pragma unroll
        for (int i = 0; i < 5; ++i) { a[i] = 0.f; d[i] = 0.f; }
        #pragma unroll
        for (int i = 0; i < 4; ++i) {
            #pragma unroll
            for (int m = 0; m < 8; ++m) {
                a[i] = fmaf(v[2*i+2+m], FLO[m], a[i]);
                d[i] = fmaf(v[2*i+2+m], FHI[m], d[i]);
            }
        }
        #pragma unroll
        for (int m = 0; m < 8; ++m) {
            d[4] = fmaf(v[10+m], FHI[m], d[4]);
            if constexpr (LAST) a[4] = fmaf(v[10+m], FLO[m], a[4]);
        }
        if constexpr (!LAST) {
            *reinterpret_cast<float4*>(dst + 4 * k) = make_float4(a[0], a[1], a[2], a[3]);
        }
        #pragma unroll
        for (int i = 0; i < 4; ++i) {
            const float ad = fabsf(d[i]);
            sabs += ad; ssum += d[i]; ssq = fmaf(d[i], d[i], ssq);
            smax = fmaxf(smax, ad);
            zc += zcstep(d[i], d[i+1]);
            if constexpr (LAST) {
                const float aa = fabsf(a[i]);
                sabsA += aa; ssumA += a[i]; ssqA = fmaf(a[i], a[i], ssqA);
                smaxA = fmaxf(smaxA, aa);
                zcA += zcstep(a[i], a[i+1]);
            }
        }
    }

    // Exactly ONE leftover quad per level for our sizes: nq-nq_main == 1.
    // Run it guarded on thread BLK-1 (low threads absorb main-loop remainders).
    if (threadIdx.x == BLK - 1) {
        const int k = nq_main;
        const int w = 8 * k - 8;
        float v[20];
        #pragma unroll
        for (int j = 2; j < 18; ++j) v[j] = getsym(src, w + j, L);
        float a[5], d[5];
        #pragma unroll
        for (int i = 0; i < 5; ++i) { a[i] = 0.f; d[i] = 0.f; }
        #pragma unroll
        for (int i = 0; i < 5; ++i) {
            #pragma unroll
            for (int m = 0; m < 8; ++m) {
                a[i] = fmaf(v[2*i+2+m], FLO[m], a[i]);
                d[i] = fmaf(v[2*i+2+m], FHI[m], d[i]);
            }
        }
        #pragma unroll
        for (int i = 0; i < 4; ++i) {
            const int p = 4 * k + i;
            if (p < o) {
                const float ad = fabsf(d[i]);
                sabs += ad; ssum += d[i]; ssq = fmaf(d[i], d[i], ssq);
                smax = fmaxf(smax, ad);
                if (p + 1 < o) zc += zcstep(d[i], d[i+1]);
                if constexpr (LAST) {
                    const float aa = fabsf(a[i]);
                    sabsA += aa; ssumA += a[i]; ssqA = fmaf(a[i], a[i], ssqA);
                    smaxA = fmaxf(smaxA, aa);
                    if (p + 1 < o) zcA += zcstep(a[i], a[i+1]);
                } else {
                    dst[p] = a[i];
                }
            }
        }
    }

    band_reduce(sabs, ssum, ssq, smax, zc, dband, red);
    if constexpr (LAST) band_reduce(sabsA, ssumA, ssqA, smaxA, zcA, 0, red);
}

__global__ void __launch_bounds__(BLK, 6)
wavelet_feat_kernel(const float* __restrict__ x, float* __restrict__ out) {
    __shared__ __align__(16) float A[8196];     // cA1, later cA3
    __shared__ __align__(16) float B[4104];     // cA2
    __shared__ float red[5 * NW * 5];           // [band][wave][stat]

    const int sig = blockIdx.x;
    const float* src0 = x + (size_t)sig * T0;
    float* outp = out + (size_t)sig * 30;

    // band index: 0=cA4 1=cD4 2=cD3 3=cD2 4=cD1
    dwt_quad_level<false>(src0, T0,   A, 8195, 4, red);   // L1: x -> A,  cD1
    __syncthreads();
    dwt_quad_level<false>(A,    8195, B, 4101, 3, red);   // L2: A -> B,  cD2
    __syncthreads();
    dwt_quad_level<false>(B,    4101, A, 2054, 2, red);   // L3: B -> A,  cD3
    __syncthreads();
    dwt_quad_level<true >(A,    2054, nullptr, 1030, 1, red); // L4: cD4 + cA4 stats
    __syncthreads();                                      // red[] complete

    if (threadIdx.x < 5) {
        const int band = threadIdx.x;
        float a = 0.f, s = 0.f, q = 0.f, m = 0.f, z = 0.f;
        #pragma unroll
        for (int w = 0; w < NW; ++w) {
            const float* r = red + (band * NW + w) * 5;
            a += r[0]; s += r[1]; q += r[2]; m = fmaxf(m, r[3]); z += r[4];
        }
        const int o = (band <= 1) ? 1030 : (band == 2 ? 2054 : (band == 3 ? 4101 : 8195));
        const float inv  = 1.0f / (float)o;
        const float mean = s * inv;
        const float var  = q * inv - mean * mean;
        float* op = outp + band * 6;
        op[0] = a * inv;                  // mean_abs
        op[1] = sqrtf(fmaxf(var, 0.f));   // std (population)
        op[2] = sqrtf(q * inv);           // rms
        op[3] = m;                        // max_abs
        op[4] = q;                        // energy
        op[5] = z * inv;                  // zero-crossing rate
    }
}

extern "C" void kernel_launch(void* const* d_in, const int* in_sizes, int n_in,
                              void* d_out, int out_size, void* d_ws, size_t ws_size,
                              hipStream_t stream) {
    const float* x = (const float*)d_in[0];
    float* out = (float*)d_out;
    const int nsig = in_sizes[0] / T0;   // 64*64 = 4096
    hipLaunchKernelGGL(wavelet_feat_kernel, dim3(nsig), dim3(BLK), 0, stream, x, out);
}